// Round 4
// baseline (492.703 us; speedup 1.0000x reference)
//
#include <hip/hip_runtime.h>

#define DD 64
#define FIN 128

// per edge: count degree + push onto dst's linked list (coalesced next[] store)
__global__ __launch_bounds__(256) void k_count_link(const int* __restrict__ dst,
                                                    int* __restrict__ deg,
                                                    int* __restrict__ head,
                                                    int* __restrict__ next, int E) {
    int e = blockIdx.x * 256 + threadIdx.x;
    if (e < E) {
        int d = dst[e];
        atomicAdd(&deg[d], 1);
        int old = atomicExch(&head[d], e);
        next[e] = old;
    }
}

// per-block sums of deg (raw edge counts)
__global__ __launch_bounds__(256) void k_scanA(const int* __restrict__ deg,
                                               int* __restrict__ partial, int n) {
    __shared__ int wsum[4];
    int i = blockIdx.x * 256 + threadIdx.x;
    int v = (i < n) ? deg[i] : 0;
    for (int off = 32; off; off >>= 1) v += __shfl_down(v, off, 64);
    int lane = threadIdx.x & 63, wid = threadIdx.x >> 6;
    if (lane == 0) wsum[wid] = v;
    __syncthreads();
    if (threadIdx.x == 0) partial[blockIdx.x] = wsum[0] + wsum[1] + wsum[2] + wsum[3];
}

// exclusive scan of partials (nb <= 512)
__global__ __launch_bounds__(512) void k_scanB(int* __restrict__ partial, int nb,
                                               int* __restrict__ total) {
    __shared__ int wsum[8];
    int v = (threadIdx.x < (unsigned)nb) ? partial[threadIdx.x] : 0;
    int lane = threadIdx.x & 63, wid = threadIdx.x >> 6;
    int s = v;
    for (int off = 1; off < 64; off <<= 1) {
        int t = __shfl_up(s, off, 64);
        if (lane >= off) s += t;
    }
    if (lane == 63) wsum[wid] = s;
    __syncthreads();
    int wo = 0;
    for (int w = 0; w < wid; ++w) wo += wsum[w];
    int excl = s - v + wo;
    if (threadIdx.x < (unsigned)nb) partial[threadIdx.x] = excl;
    if (threadIdx.x == (unsigned)(nb - 1)) *total = excl + v;
}

// per-block exclusive scan + block offset -> rowptr; rs = rsqrt(deg+1)
__global__ __launch_bounds__(256) void k_scanC(const int* __restrict__ deg,
                                               const int* __restrict__ partial,
                                               int* __restrict__ rowptr,
                                               float* __restrict__ rs, int n) {
    __shared__ int wsum[4];
    int i = blockIdx.x * 256 + threadIdx.x;
    int v = (i < n) ? deg[i] : 0;
    int lane = threadIdx.x & 63, wid = threadIdx.x >> 6;
    int s = v;
    for (int off = 1; off < 64; off <<= 1) {
        int t = __shfl_up(s, off, 64);
        if (lane >= off) s += t;
    }
    if (lane == 63) wsum[wid] = s;
    __syncthreads();
    int wo = partial[blockIdx.x];
    for (int w = 0; w < wid; ++w) wo += wsum[w];
    int excl = s - v + wo;
    if (i < n) {
        rowptr[i] = excl;
        rs[i] = rsqrtf((float)(v + 1));
    }
}

// one lane per node: walk linked list, emit CSR column array (sequential writes)
__global__ __launch_bounds__(256) void k_list2csr(const int* __restrict__ src,
                                                  const int* __restrict__ head,
                                                  const int* __restrict__ next,
                                                  const int* __restrict__ rowptr,
                                                  int* __restrict__ es, int n) {
    int i = blockIdx.x * 256 + threadIdx.x;
    if (i >= n) return;
    int pos = rowptr[i];
    int e = head[i];
    while (e >= 0) {
        es[pos++] = src[e];
        e = next[e];
    }
}

// out[row][col] = (x[row,:] @ W[:,col]) * rs[row]  -- W column in VGPRs, x scalar loads
__global__ __launch_bounds__(256) void k_gemm1(const float* __restrict__ x,
                                               const float* __restrict__ W,
                                               const float* __restrict__ rs,
                                               float* __restrict__ out, int n) {
    int col = threadIdx.x & 63;
    int wid = threadIdx.x >> 6;
    float w[FIN];
#pragma unroll
    for (int k = 0; k < FIN; ++k) w[k] = W[k * DD + col];
    int wave = blockIdx.x * 4 + wid;
    int nw = gridDim.x * 4;
    for (int row = wave; row < n; row += nw) {
        int urow = __builtin_amdgcn_readfirstlane(row);
        const float* xr = x + (size_t)urow * FIN;
        float a0 = 0.f, a1 = 0.f, a2 = 0.f, a3 = 0.f;
#pragma unroll
        for (int k = 0; k < FIN; k += 4) {
            a0 = fmaf(xr[k],     w[k],     a0);
            a1 = fmaf(xr[k + 1], w[k + 1], a1);
            a2 = fmaf(xr[k + 2], w[k + 2], a2);
            a3 = fmaf(xr[k + 3], w[k + 3], a3);
        }
        out[(size_t)urow * DD + col] = (a0 + a1 + a2 + a3) * rs[urow];
    }
}

// out[row][col] = (relu(a[row,:]) @ W[:,col]) * rs[row]
__global__ __launch_bounds__(256) void k_gemm2(const float* __restrict__ a,
                                               const float* __restrict__ W,
                                               const float* __restrict__ rs,
                                               float* __restrict__ out, int n) {
    int col = threadIdx.x & 63;
    int wid = threadIdx.x >> 6;
    float w[DD];
#pragma unroll
    for (int k = 0; k < DD; ++k) w[k] = W[k * DD + col];
    int wave = blockIdx.x * 4 + wid;
    int nw = gridDim.x * 4;
    for (int row = wave; row < n; row += nw) {
        int urow = __builtin_amdgcn_readfirstlane(row);
        const float* ar = a + (size_t)urow * DD;
        float a0 = 0.f, a1 = 0.f, a2 = 0.f, a3 = 0.f;
#pragma unroll
        for (int k = 0; k < DD; k += 4) {
            a0 = fmaf(fmaxf(ar[k],     0.f), w[k],     a0);
            a1 = fmaf(fmaxf(ar[k + 1], 0.f), w[k + 1], a1);
            a2 = fmaf(fmaxf(ar[k + 2], 0.f), w[k + 2], a2);
            a3 = fmaf(fmaxf(ar[k + 3], 0.f), w[k + 3], a3);
        }
        out[(size_t)urow * DD + col] = (a0 + a1 + a2 + a3) * rs[urow];
    }
}

// gather aggregation: one wave per node; 4 groups x 16 lanes; group gathers one
// edge's hp row as float4. out[d] = b + pert[d] + rs[d]*(hp[d] + sum hp[src])
__global__ __launch_bounds__(256) void k_agg(const float* __restrict__ hp,
                                             const int* __restrict__ es,
                                             const int* __restrict__ rowptr,
                                             const float* __restrict__ rs,
                                             const float* __restrict__ b,
                                             const float* __restrict__ pert,
                                             float* __restrict__ outp, int n) {
    int lane = threadIdx.x & 63;
    int w = threadIdx.x >> 6;
    int node = blockIdx.x * 4 + w;
    if (node >= n) return;
    node = __builtin_amdgcn_readfirstlane(node);
    int grp = lane >> 4, sub = lane & 15;
    int e0 = rowptr[node], e1 = rowptr[node + 1];
    float4 acc0 = make_float4(0.f, 0.f, 0.f, 0.f);
    float4 acc1 = make_float4(0.f, 0.f, 0.f, 0.f);
    if (grp == 0)  // self-loop term
        acc0 = *(const float4*)(hp + (size_t)node * DD + sub * 4);
    int e = e0 + grp;
    for (; e + 4 < e1; e += 8) {
        int sA = es[e];
        int sB = es[e + 4];
        float4 va = *(const float4*)(hp + (size_t)sA * DD + sub * 4);
        float4 vb = *(const float4*)(hp + (size_t)sB * DD + sub * 4);
        acc0.x += va.x; acc0.y += va.y; acc0.z += va.z; acc0.w += va.w;
        acc1.x += vb.x; acc1.y += vb.y; acc1.z += vb.z; acc1.w += vb.w;
    }
    if (e < e1) {
        int s = es[e];
        float4 v = *(const float4*)(hp + (size_t)s * DD + sub * 4);
        acc0.x += v.x; acc0.y += v.y; acc0.z += v.z; acc0.w += v.w;
    }
    acc0.x += acc1.x; acc0.y += acc1.y; acc0.z += acc1.z; acc0.w += acc1.w;
    // combine the 4 groups
    acc0.x += __shfl_xor(acc0.x, 16, 64);
    acc0.y += __shfl_xor(acc0.y, 16, 64);
    acc0.z += __shfl_xor(acc0.z, 16, 64);
    acc0.w += __shfl_xor(acc0.w, 16, 64);
    acc0.x += __shfl_xor(acc0.x, 32, 64);
    acc0.y += __shfl_xor(acc0.y, 32, 64);
    acc0.z += __shfl_xor(acc0.z, 32, 64);
    acc0.w += __shfl_xor(acc0.w, 32, 64);
    if (grp == 0) {
        size_t o = (size_t)node * DD + sub * 4;
        float4 p = *(const float4*)(pert + o);
        float4 bb = *(const float4*)(b + sub * 4);
        float r = rs[node];
        float4 res;
        res.x = fmaf(r, acc0.x, bb.x + p.x);
        res.y = fmaf(r, acc0.y, bb.y + p.y);
        res.z = fmaf(r, acc0.z, bb.z + p.z);
        res.w = fmaf(r, acc0.w, bb.w + p.w);
        *(float4*)(outp + o) = res;
    }
}

extern "C" void kernel_launch(void* const* d_in, const int* in_sizes, int n_in,
                              void* d_out, int out_size, void* d_ws, size_t ws_size,
                              hipStream_t stream) {
    const float* x  = (const float*)d_in[0];
    const int*   ei = (const int*)d_in[1];
    const float* W1 = (const float*)d_in[2];
    const float* b1 = (const float*)d_in[3];
    const float* W2 = (const float*)d_in[4];
    const float* b2 = (const float*)d_in[5];
    const float* p1 = (const float*)d_in[6];
    const float* p2 = (const float*)d_in[7];
    float* out = (float*)d_out;

    int n = in_sizes[0] / FIN;
    int E = in_sizes[1] / 2;
    const int* src = ei;
    const int* dst = ei + E;

    char* ws = (char*)d_ws;
    size_t off = 0;
    int* deg     = (int*)(ws + off); off += sizeof(int) * (size_t)n;
    int* partial = (int*)(ws + off); off += sizeof(int) * 512;
    int* rowptr  = (int*)(ws + off); off += sizeof(int) * (size_t)(n + 1);
    float* rs    = (float*)(ws + off); off += sizeof(float) * (size_t)n;
    int* head    = (int*)(ws + off); off += sizeof(int) * (size_t)n;
    int* nxt     = (int*)(ws + off); off += sizeof(int) * (size_t)E;
    int* es      = (int*)(ws + off); off += sizeof(int) * (size_t)E;
    float* h1    = (float*)(ws + off); off += sizeof(float) * (size_t)n * DD;  // reused as h2
    float* agg1  = (float*)(ws + off); off += sizeof(float) * (size_t)n * DD;

    int nb = (n + 255) / 256;   // 391 <= 512 for n=100k
    int eb = (E + 255) / 256;
    int ab = (n + 3) / 4;

    hipMemsetAsync(deg, 0, sizeof(int) * (size_t)n, stream);
    hipMemsetAsync(head, 0xFF, sizeof(int) * (size_t)n, stream);  // head = -1
    k_count_link<<<eb, 256, 0, stream>>>(dst, deg, head, nxt, E);
    k_scanA<<<nb, 256, 0, stream>>>(deg, partial, n);
    k_scanB<<<1, 512, 0, stream>>>(partial, nb, rowptr + n);
    k_scanC<<<nb, 256, 0, stream>>>(deg, partial, rowptr, rs, n);
    k_list2csr<<<nb, 256, 0, stream>>>(src, head, nxt, rowptr, es, n);

    k_gemm1<<<1024, 256, 0, stream>>>(x, W1, rs, h1, n);
    k_agg<<<ab, 256, 0, stream>>>(h1, es, rowptr, rs, b1, p1, agg1, n);

    k_gemm2<<<1024, 256, 0, stream>>>(agg1, W2, rs, h1, n);
    k_agg<<<ab, 256, 0, stream>>>(h1, es, rowptr, rs, b2, p2, out, n);
}

// Round 5
// 323.901 us; speedup vs baseline: 1.5212x; 1.5212x over previous
//
#include <hip/hip_runtime.h>

#define DD 64
#define FIN 128
#define BK 256        // nodes per bucket
#define MAXBUK 512    // supports n <= 131072
#define CAP 8192      // records per bucket region (mean ~4092 at E=1.6M)

// pass 1: bucket edges by dst>>8. LDS histogram -> one global atomic per
// (block,bucket) to reserve a range -> scatter packed (src,dst) records.
__global__ __launch_bounds__(256) void k_bucket(const int* __restrict__ src,
                                                const int* __restrict__ dst,
                                                unsigned long long* __restrict__ buf,
                                                int* __restrict__ gcur,
                                                int E, int nbuk) {
    __shared__ int hist[MAXBUK];
    __shared__ int base[MAXBUK];
    int nb = gridDim.x;
    int chunk = (E + nb - 1) / nb;
    int e0 = blockIdx.x * chunk;
    int e1 = min(e0 + chunk, E);
    for (int i = threadIdx.x; i < nbuk; i += 256) hist[i] = 0;
    __syncthreads();
    for (int e = e0 + threadIdx.x; e < e1; e += 256)
        atomicAdd(&hist[dst[e] >> 8], 1);
    __syncthreads();
    for (int i = threadIdx.x; i < nbuk; i += 256) {
        int c = hist[i];
        base[i] = c ? atomicAdd(&gcur[i], c) : 0;
        hist[i] = 0;  // reuse as local cursor
    }
    __syncthreads();
    for (int e = e0 + threadIdx.x; e < e1; e += 256) {
        int d = dst[e];
        int b = d >> 8;
        int off = base[b] + atomicAdd(&hist[b], 1);
        if (off < CAP)
            buf[(size_t)b * CAP + off] =
                ((unsigned long long)(unsigned)src[e] << 32) | (unsigned)d;
    }
}

// exclusive scan of bucket counts -> bucket base offsets; rowptr[n] = E
__global__ __launch_bounds__(512) void k_scanbuk(const int* __restrict__ gcur,
                                                 int* __restrict__ bbase, int nbuk,
                                                 int* __restrict__ rowptr_n, int E) {
    __shared__ int wsum[8];
    int v = (threadIdx.x < (unsigned)nbuk) ? gcur[threadIdx.x] : 0;
    int lane = threadIdx.x & 63, wid = threadIdx.x >> 6;
    int s = v;
    for (int off = 1; off < 64; off <<= 1) {
        int t = __shfl_up(s, off, 64);
        if (lane >= off) s += t;
    }
    if (lane == 63) wsum[wid] = s;
    __syncthreads();
    int wo = 0;
    for (int w = 0; w < wid; ++w) wo += wsum[w];
    if (threadIdx.x < (unsigned)nbuk) bbase[threadIdx.x] = s - v + wo;
    if (threadIdx.x == 0) *rowptr_n = E;
}

// pass 2: one workgroup per bucket -> per-node counts, scan, emit rowptr/rs/es
__global__ __launch_bounds__(256) void k_csr(const unsigned long long* __restrict__ buf,
                                             const int* __restrict__ gcur,
                                             const int* __restrict__ bbase,
                                             int* __restrict__ rowptr,
                                             float* __restrict__ rs,
                                             int* __restrict__ es, int n) {
    __shared__ int cnt[BK];
    __shared__ int excl[BK];
    __shared__ int cur[BK];
    __shared__ int wsum[4];
    int b = blockIdx.x;
    int count = gcur[b];
    int base = bbase[b];
    cnt[threadIdx.x] = 0;
    cur[threadIdx.x] = 0;
    __syncthreads();
    const unsigned long long* rec = buf + (size_t)b * CAP;
    for (int i = threadIdx.x; i < count; i += 256)
        atomicAdd(&cnt[(unsigned)rec[i] & (BK - 1)], 1);
    __syncthreads();
    int lane = threadIdx.x & 63, wid = threadIdx.x >> 6;
    int v = cnt[threadIdx.x];
    int s = v;
    for (int off = 1; off < 64; off <<= 1) {
        int t = __shfl_up(s, off, 64);
        if (lane >= off) s += t;
    }
    if (lane == 63) wsum[wid] = s;
    __syncthreads();
    int wo = 0;
    for (int w = 0; w < wid; ++w) wo += wsum[w];
    excl[threadIdx.x] = s - v + wo;
    __syncthreads();
    int node = b * BK + threadIdx.x;
    if (node < n) {
        rowptr[node] = base + excl[threadIdx.x];
        rs[node] = rsqrtf((float)(v + 1));  // +1 self-loop
    }
    for (int i = threadIdx.x; i < count; i += 256) {
        unsigned long long r = rec[i];
        int local = (unsigned)r & (BK - 1);
        int pos = base + excl[local] + atomicAdd(&cur[local], 1);
        es[pos] = (int)(r >> 32);
    }
}

// out[row][col] = (x[row,:] @ W[:,col]) * rs[row]  -- W column in VGPRs, x scalar loads
__global__ __launch_bounds__(256) void k_gemm1(const float* __restrict__ x,
                                               const float* __restrict__ W,
                                               const float* __restrict__ rs,
                                               float* __restrict__ out, int n) {
    int col = threadIdx.x & 63;
    int wid = threadIdx.x >> 6;
    float w[FIN];
#pragma unroll
    for (int k = 0; k < FIN; ++k) w[k] = W[k * DD + col];
    int wave = blockIdx.x * 4 + wid;
    int nw = gridDim.x * 4;
    for (int row = wave; row < n; row += nw) {
        int urow = __builtin_amdgcn_readfirstlane(row);
        const float* xr = x + (size_t)urow * FIN;
        float a0 = 0.f, a1 = 0.f, a2 = 0.f, a3 = 0.f;
#pragma unroll
        for (int k = 0; k < FIN; k += 4) {
            a0 = fmaf(xr[k],     w[k],     a0);
            a1 = fmaf(xr[k + 1], w[k + 1], a1);
            a2 = fmaf(xr[k + 2], w[k + 2], a2);
            a3 = fmaf(xr[k + 3], w[k + 3], a3);
        }
        out[(size_t)urow * DD + col] = (a0 + a1 + a2 + a3) * rs[urow];
    }
}

// out[row][col] = (relu(a[row,:]) @ W[:,col]) * rs[row]
__global__ __launch_bounds__(256) void k_gemm2(const float* __restrict__ a,
                                               const float* __restrict__ W,
                                               const float* __restrict__ rs,
                                               float* __restrict__ out, int n) {
    int col = threadIdx.x & 63;
    int wid = threadIdx.x >> 6;
    float w[DD];
#pragma unroll
    for (int k = 0; k < DD; ++k) w[k] = W[k * DD + col];
    int wave = blockIdx.x * 4 + wid;
    int nw = gridDim.x * 4;
    for (int row = wave; row < n; row += nw) {
        int urow = __builtin_amdgcn_readfirstlane(row);
        const float* ar = a + (size_t)urow * DD;
        float a0 = 0.f, a1 = 0.f, a2 = 0.f, a3 = 0.f;
#pragma unroll
        for (int k = 0; k < DD; k += 4) {
            a0 = fmaf(fmaxf(ar[k],     0.f), w[k],     a0);
            a1 = fmaf(fmaxf(ar[k + 1], 0.f), w[k + 1], a1);
            a2 = fmaf(fmaxf(ar[k + 2], 0.f), w[k + 2], a2);
            a3 = fmaf(fmaxf(ar[k + 3], 0.f), w[k + 3], a3);
        }
        out[(size_t)urow * DD + col] = (a0 + a1 + a2 + a3) * rs[urow];
    }
}

// gather aggregation: one wave per node; 4 groups x 16 lanes; group gathers one
// edge's hp row as float4. out[d] = b + pert[d] + rs[d]*(hp[d] + sum hp[src])
__global__ __launch_bounds__(256) void k_agg(const float* __restrict__ hp,
                                             const int* __restrict__ es,
                                             const int* __restrict__ rowptr,
                                             const float* __restrict__ rs,
                                             const float* __restrict__ b,
                                             const float* __restrict__ pert,
                                             float* __restrict__ outp, int n) {
    int lane = threadIdx.x & 63;
    int w = threadIdx.x >> 6;
    int node = blockIdx.x * 4 + w;
    if (node >= n) return;
    node = __builtin_amdgcn_readfirstlane(node);
    int grp = lane >> 4, sub = lane & 15;
    int e0 = rowptr[node], e1 = rowptr[node + 1];
    float4 acc0 = make_float4(0.f, 0.f, 0.f, 0.f);
    float4 acc1 = make_float4(0.f, 0.f, 0.f, 0.f);
    if (grp == 0)  // self-loop term
        acc0 = *(const float4*)(hp + (size_t)node * DD + sub * 4);
    int e = e0 + grp;
    for (; e + 4 < e1; e += 8) {
        int sA = es[e];
        int sB = es[e + 4];
        float4 va = *(const float4*)(hp + (size_t)sA * DD + sub * 4);
        float4 vb = *(const float4*)(hp + (size_t)sB * DD + sub * 4);
        acc0.x += va.x; acc0.y += va.y; acc0.z += va.z; acc0.w += va.w;
        acc1.x += vb.x; acc1.y += vb.y; acc1.z += vb.z; acc1.w += vb.w;
    }
    if (e < e1) {
        int s = es[e];
        float4 v = *(const float4*)(hp + (size_t)s * DD + sub * 4);
        acc0.x += v.x; acc0.y += v.y; acc0.z += v.z; acc0.w += v.w;
    }
    acc0.x += acc1.x; acc0.y += acc1.y; acc0.z += acc1.z; acc0.w += acc1.w;
    acc0.x += __shfl_xor(acc0.x, 16, 64);
    acc0.y += __shfl_xor(acc0.y, 16, 64);
    acc0.z += __shfl_xor(acc0.z, 16, 64);
    acc0.w += __shfl_xor(acc0.w, 16, 64);
    acc0.x += __shfl_xor(acc0.x, 32, 64);
    acc0.y += __shfl_xor(acc0.y, 32, 64);
    acc0.z += __shfl_xor(acc0.z, 32, 64);
    acc0.w += __shfl_xor(acc0.w, 32, 64);
    if (grp == 0) {
        size_t o = (size_t)node * DD + sub * 4;
        float4 p = *(const float4*)(pert + o);
        float4 bb = *(const float4*)(b + sub * 4);
        float r = rs[node];
        float4 res;
        res.x = fmaf(r, acc0.x, bb.x + p.x);
        res.y = fmaf(r, acc0.y, bb.y + p.y);
        res.z = fmaf(r, acc0.z, bb.z + p.z);
        res.w = fmaf(r, acc0.w, bb.w + p.w);
        *(float4*)(outp + o) = res;
    }
}

extern "C" void kernel_launch(void* const* d_in, const int* in_sizes, int n_in,
                              void* d_out, int out_size, void* d_ws, size_t ws_size,
                              hipStream_t stream) {
    const float* x  = (const float*)d_in[0];
    const int*   ei = (const int*)d_in[1];
    const float* W1 = (const float*)d_in[2];
    const float* b1 = (const float*)d_in[3];
    const float* W2 = (const float*)d_in[4];
    const float* b2 = (const float*)d_in[5];
    const float* p1 = (const float*)d_in[6];
    const float* p2 = (const float*)d_in[7];
    float* out = (float*)d_out;

    int n = in_sizes[0] / FIN;
    int E = in_sizes[1] / 2;
    const int* src = ei;
    const int* dst = ei + E;
    int nbuk = (n + BK - 1) / BK;  // 391 for n=100k

    char* ws = (char*)d_ws;
    size_t off = 0;
    int* gcur   = (int*)(ws + off); off += sizeof(int) * MAXBUK;
    int* bbase  = (int*)(ws + off); off += sizeof(int) * MAXBUK;
    int* rowptr = (int*)(ws + off); off += sizeof(int) * (size_t)(n + 1);
    float* rs   = (float*)(ws + off); off += sizeof(float) * (size_t)n;
    int* es     = (int*)(ws + off); off += sizeof(int) * (size_t)E;
    off = (off + 15) & ~(size_t)15;
    unsigned long long* buf = (unsigned long long*)(ws + off);
    off += sizeof(unsigned long long) * (size_t)nbuk * CAP;
    float* h1   = (float*)(ws + off); off += sizeof(float) * (size_t)n * DD;  // also h2
    float* agg1 = (float*)(ws + off); off += sizeof(float) * (size_t)n * DD;

    int ab = (n + 3) / 4;

    hipMemsetAsync(gcur, 0, sizeof(int) * MAXBUK, stream);
    k_bucket<<<nbuk, 256, 0, stream>>>(src, dst, buf, gcur, E, nbuk);
    k_scanbuk<<<1, 512, 0, stream>>>(gcur, bbase, nbuk, rowptr + n, E);
    k_csr<<<nbuk, 256, 0, stream>>>(buf, gcur, bbase, rowptr, rs, es, n);

    k_gemm1<<<1024, 256, 0, stream>>>(x, W1, rs, h1, n);
    k_agg<<<ab, 256, 0, stream>>>(h1, es, rowptr, rs, b1, p1, agg1, n);

    k_gemm2<<<1024, 256, 0, stream>>>(agg1, W2, rs, h1, n);
    k_agg<<<ab, 256, 0, stream>>>(h1, es, rowptr, rs, b2, p2, out, n);
}

// Round 6
// 299.489 us; speedup vs baseline: 1.6451x; 1.0815x over previous
//
#include <hip/hip_runtime.h>

#define DD 64
#define FIN 128
#define BK 256        // nodes per bucket
#define MAXBUK 512    // supports n <= 131072
#define CAP 8192      // records per bucket region (mean ~4092 at E=1.6M)

#define XS1 132       // padded x-tile stride (floats) for gemm1
#define XS2 68        // padded x-tile stride (floats) for gemm2

static __device__ __forceinline__ float4 f4fma(float a, float4 b, float4 c) {
    c.x = fmaf(a, b.x, c.x);
    c.y = fmaf(a, b.y, c.y);
    c.z = fmaf(a, b.z, c.z);
    c.w = fmaf(a, b.w, c.w);
    return c;
}

// pass 1: bucket edges by dst>>8. LDS histogram -> one global atomic per
// (block,bucket) to reserve a range -> scatter packed (src,dst) records.
__global__ __launch_bounds__(256) void k_bucket(const int* __restrict__ src,
                                                const int* __restrict__ dst,
                                                unsigned long long* __restrict__ buf,
                                                int* __restrict__ gcur,
                                                int E, int nbuk) {
    __shared__ int hist[MAXBUK];
    __shared__ int base[MAXBUK];
    int nb = gridDim.x;
    int chunk = (E + nb - 1) / nb;
    int e0 = blockIdx.x * chunk;
    int e1 = min(e0 + chunk, E);
    for (int i = threadIdx.x; i < nbuk; i += 256) hist[i] = 0;
    __syncthreads();
    for (int e = e0 + threadIdx.x; e < e1; e += 256)
        atomicAdd(&hist[dst[e] >> 8], 1);
    __syncthreads();
    for (int i = threadIdx.x; i < nbuk; i += 256) {
        int c = hist[i];
        base[i] = c ? atomicAdd(&gcur[i], c) : 0;
        hist[i] = 0;  // reuse as local cursor
    }
    __syncthreads();
    for (int e = e0 + threadIdx.x; e < e1; e += 256) {
        int d = dst[e];
        int b = d >> 8;
        int off = base[b] + atomicAdd(&hist[b], 1);
        if (off < CAP)
            buf[(size_t)b * CAP + off] =
                ((unsigned long long)(unsigned)src[e] << 32) | (unsigned)d;
    }
}

// exclusive scan of bucket counts -> bucket base offsets; rowptr[n] = E
__global__ __launch_bounds__(512) void k_scanbuk(const int* __restrict__ gcur,
                                                 int* __restrict__ bbase, int nbuk,
                                                 int* __restrict__ rowptr_n, int E) {
    __shared__ int wsum[8];
    int v = (threadIdx.x < (unsigned)nbuk) ? gcur[threadIdx.x] : 0;
    int lane = threadIdx.x & 63, wid = threadIdx.x >> 6;
    int s = v;
    for (int off = 1; off < 64; off <<= 1) {
        int t = __shfl_up(s, off, 64);
        if (lane >= off) s += t;
    }
    if (lane == 63) wsum[wid] = s;
    __syncthreads();
    int wo = 0;
    for (int w = 0; w < wid; ++w) wo += wsum[w];
    if (threadIdx.x < (unsigned)nbuk) bbase[threadIdx.x] = s - v + wo;
    if (threadIdx.x == 0) *rowptr_n = E;
}

// pass 2: one workgroup per bucket -> per-node counts, scan, emit rowptr/rs/es
__global__ __launch_bounds__(256) void k_csr(const unsigned long long* __restrict__ buf,
                                             const int* __restrict__ gcur,
                                             const int* __restrict__ bbase,
                                             int* __restrict__ rowptr,
                                             float* __restrict__ rs,
                                             int* __restrict__ es, int n) {
    __shared__ int cnt[BK];
    __shared__ int excl[BK];
    __shared__ int cur[BK];
    __shared__ int wsum[4];
    int b = blockIdx.x;
    int count = gcur[b];
    int base = bbase[b];
    cnt[threadIdx.x] = 0;
    cur[threadIdx.x] = 0;
    __syncthreads();
    const unsigned long long* rec = buf + (size_t)b * CAP;
    for (int i = threadIdx.x; i < count; i += 256)
        atomicAdd(&cnt[(unsigned)rec[i] & (BK - 1)], 1);
    __syncthreads();
    int lane = threadIdx.x & 63, wid = threadIdx.x >> 6;
    int v = cnt[threadIdx.x];
    int s = v;
    for (int off = 1; off < 64; off <<= 1) {
        int t = __shfl_up(s, off, 64);
        if (lane >= off) s += t;
    }
    if (lane == 63) wsum[wid] = s;
    __syncthreads();
    int wo = 0;
    for (int w = 0; w < wid; ++w) wo += wsum[w];
    excl[threadIdx.x] = s - v + wo;
    __syncthreads();
    int node = b * BK + threadIdx.x;
    if (node < n) {
        rowptr[node] = base + excl[threadIdx.x];
        rs[node] = rsqrtf((float)(v + 1));  // +1 self-loop
    }
    for (int i = threadIdx.x; i < count; i += 256) {
        unsigned long long r = rec[i];
        int local = (unsigned)r & (BK - 1);
        int pos = base + excl[local] + atomicAdd(&cur[local], 1);
        es[pos] = (int)(r >> 32);
    }
}

// LDS-tiled GEMM: out[64rows x 64cols] per block, thread = 4x4 tile.
// out[row][col] = (x[row,:] @ W[:,col]) * rs[row]
__global__ __launch_bounds__(256) void k_gemm1(const float* __restrict__ x,
                                               const float* __restrict__ W,
                                               const float* __restrict__ rs,
                                               float* __restrict__ out, int n) {
    __shared__ float sx[64 * XS1];
    __shared__ float sW[FIN * DD];
    int row0 = blockIdx.x * 64;
    for (int i = threadIdx.x; i < FIN * DD / 4; i += 256)
        ((float4*)sW)[i] = ((const float4*)W)[i];
    for (int i = threadIdx.x; i < 64 * FIN / 4; i += 256) {
        int r = i >> 5;           // 32 float4 per row
        int c = i & 31;
        int row = row0 + r;
        float4 v = make_float4(0.f, 0.f, 0.f, 0.f);
        if (row < n) v = *(const float4*)(x + (size_t)row * FIN + c * 4);
        *(float4*)(sx + r * XS1 + c * 4) = v;
    }
    __syncthreads();
    int col4 = (threadIdx.x & 15) * 4;
    int rowg = threadIdx.x >> 4;  // 0..15
    float4 acc[4] = {make_float4(0,0,0,0), make_float4(0,0,0,0),
                     make_float4(0,0,0,0), make_float4(0,0,0,0)};
#pragma unroll 8
    for (int k = 0; k < FIN; k += 4) {
        float4 w0 = *(const float4*)(sW + k * DD + col4);
        float4 w1 = *(const float4*)(sW + (k + 1) * DD + col4);
        float4 w2 = *(const float4*)(sW + (k + 2) * DD + col4);
        float4 w3 = *(const float4*)(sW + (k + 3) * DD + col4);
#pragma unroll
        for (int r = 0; r < 4; ++r) {
            float4 xv = *(const float4*)(sx + (rowg * 4 + r) * XS1 + k);
            acc[r] = f4fma(xv.x, w0, acc[r]);
            acc[r] = f4fma(xv.y, w1, acc[r]);
            acc[r] = f4fma(xv.z, w2, acc[r]);
            acc[r] = f4fma(xv.w, w3, acc[r]);
        }
    }
#pragma unroll
    for (int r = 0; r < 4; ++r) {
        int row = row0 + rowg * 4 + r;
        if (row < n) {
            float sc = rs[row];
            float4 res = acc[r];
            res.x *= sc; res.y *= sc; res.z *= sc; res.w *= sc;
            *(float4*)(out + (size_t)row * DD + col4) = res;
        }
    }
}

// out[row][col] = (relu(a[row,:]) @ W[:,col]) * rs[row]
__global__ __launch_bounds__(256) void k_gemm2(const float* __restrict__ a,
                                               const float* __restrict__ W,
                                               const float* __restrict__ rs,
                                               float* __restrict__ out, int n) {
    __shared__ float sx[64 * XS2];
    __shared__ float sW[DD * DD];
    int row0 = blockIdx.x * 64;
    for (int i = threadIdx.x; i < DD * DD / 4; i += 256)
        ((float4*)sW)[i] = ((const float4*)W)[i];
    for (int i = threadIdx.x; i < 64 * DD / 4; i += 256) {
        int r = i >> 4;           // 16 float4 per row
        int c = i & 15;
        int row = row0 + r;
        float4 v = make_float4(0.f, 0.f, 0.f, 0.f);
        if (row < n) {
            v = *(const float4*)(a + (size_t)row * DD + c * 4);
            v.x = fmaxf(v.x, 0.f); v.y = fmaxf(v.y, 0.f);
            v.z = fmaxf(v.z, 0.f); v.w = fmaxf(v.w, 0.f);
        }
        *(float4*)(sx + r * XS2 + c * 4) = v;
    }
    __syncthreads();
    int col4 = (threadIdx.x & 15) * 4;
    int rowg = threadIdx.x >> 4;
    float4 acc[4] = {make_float4(0,0,0,0), make_float4(0,0,0,0),
                     make_float4(0,0,0,0), make_float4(0,0,0,0)};
#pragma unroll 8
    for (int k = 0; k < DD; k += 4) {
        float4 w0 = *(const float4*)(sW + k * DD + col4);
        float4 w1 = *(const float4*)(sW + (k + 1) * DD + col4);
        float4 w2 = *(const float4*)(sW + (k + 2) * DD + col4);
        float4 w3 = *(const float4*)(sW + (k + 3) * DD + col4);
#pragma unroll
        for (int r = 0; r < 4; ++r) {
            float4 xv = *(const float4*)(sx + (rowg * 4 + r) * XS2 + k);
            acc[r] = f4fma(xv.x, w0, acc[r]);
            acc[r] = f4fma(xv.y, w1, acc[r]);
            acc[r] = f4fma(xv.z, w2, acc[r]);
            acc[r] = f4fma(xv.w, w3, acc[r]);
        }
    }
#pragma unroll
    for (int r = 0; r < 4; ++r) {
        int row = row0 + rowg * 4 + r;
        if (row < n) {
            float sc = rs[row];
            float4 res = acc[r];
            res.x *= sc; res.y *= sc; res.z *= sc; res.w *= sc;
            *(float4*)(out + (size_t)row * DD + col4) = res;
        }
    }
}

// gather aggregation: one wave per node; 4 groups x 16 lanes; group gathers one
// edge's hp row as float4. out[d] = b + pert[d] + rs[d]*(hp[d] + sum hp[src])
__global__ __launch_bounds__(256) void k_agg(const float* __restrict__ hp,
                                             const int* __restrict__ es,
                                             const int* __restrict__ rowptr,
                                             const float* __restrict__ rs,
                                             const float* __restrict__ b,
                                             const float* __restrict__ pert,
                                             float* __restrict__ outp, int n) {
    int lane = threadIdx.x & 63;
    int w = threadIdx.x >> 6;
    int node = blockIdx.x * 4 + w;
    if (node >= n) return;
    node = __builtin_amdgcn_readfirstlane(node);
    int grp = lane >> 4, sub = lane & 15;
    int e0 = rowptr[node], e1 = rowptr[node + 1];
    float4 acc0 = make_float4(0.f, 0.f, 0.f, 0.f);
    float4 acc1 = make_float4(0.f, 0.f, 0.f, 0.f);
    if (grp == 0)  // self-loop term
        acc0 = *(const float4*)(hp + (size_t)node * DD + sub * 4);
    int e = e0 + grp;
    for (; e + 4 < e1; e += 8) {
        int sA = es[e];
        int sB = es[e + 4];
        float4 va = *(const float4*)(hp + (size_t)sA * DD + sub * 4);
        float4 vb = *(const float4*)(hp + (size_t)sB * DD + sub * 4);
        acc0.x += va.x; acc0.y += va.y; acc0.z += va.z; acc0.w += va.w;
        acc1.x += vb.x; acc1.y += vb.y; acc1.z += vb.z; acc1.w += vb.w;
    }
    if (e < e1) {
        int s = es[e];
        float4 v = *(const float4*)(hp + (size_t)s * DD + sub * 4);
        acc0.x += v.x; acc0.y += v.y; acc0.z += v.z; acc0.w += v.w;
    }
    acc0.x += acc1.x; acc0.y += acc1.y; acc0.z += acc1.z; acc0.w += acc1.w;
    acc0.x += __shfl_xor(acc0.x, 16, 64);
    acc0.y += __shfl_xor(acc0.y, 16, 64);
    acc0.z += __shfl_xor(acc0.z, 16, 64);
    acc0.w += __shfl_xor(acc0.w, 16, 64);
    acc0.x += __shfl_xor(acc0.x, 32, 64);
    acc0.y += __shfl_xor(acc0.y, 32, 64);
    acc0.z += __shfl_xor(acc0.z, 32, 64);
    acc0.w += __shfl_xor(acc0.w, 32, 64);
    if (grp == 0) {
        size_t o = (size_t)node * DD + sub * 4;
        float4 p = *(const float4*)(pert + o);
        float4 bb = *(const float4*)(b + sub * 4);
        float r = rs[node];
        float4 res;
        res.x = fmaf(r, acc0.x, bb.x + p.x);
        res.y = fmaf(r, acc0.y, bb.y + p.y);
        res.z = fmaf(r, acc0.z, bb.z + p.z);
        res.w = fmaf(r, acc0.w, bb.w + p.w);
        *(float4*)(outp + o) = res;
    }
}

extern "C" void kernel_launch(void* const* d_in, const int* in_sizes, int n_in,
                              void* d_out, int out_size, void* d_ws, size_t ws_size,
                              hipStream_t stream) {
    const float* x  = (const float*)d_in[0];
    const int*   ei = (const int*)d_in[1];
    const float* W1 = (const float*)d_in[2];
    const float* b1 = (const float*)d_in[3];
    const float* W2 = (const float*)d_in[4];
    const float* b2 = (const float*)d_in[5];
    const float* p1 = (const float*)d_in[6];
    const float* p2 = (const float*)d_in[7];
    float* out = (float*)d_out;

    int n = in_sizes[0] / FIN;
    int E = in_sizes[1] / 2;
    const int* src = ei;
    const int* dst = ei + E;
    int nbuk = (n + BK - 1) / BK;  // 391 for n=100k

    char* ws = (char*)d_ws;
    size_t off = 0;
    int* gcur   = (int*)(ws + off); off += sizeof(int) * MAXBUK;
    int* bbase  = (int*)(ws + off); off += sizeof(int) * MAXBUK;
    int* rowptr = (int*)(ws + off); off += sizeof(int) * (size_t)(n + 1);
    float* rs   = (float*)(ws + off); off += sizeof(float) * (size_t)n;
    int* es     = (int*)(ws + off); off += sizeof(int) * (size_t)E;
    off = (off + 15) & ~(size_t)15;
    unsigned long long* buf = (unsigned long long*)(ws + off);
    off += sizeof(unsigned long long) * (size_t)nbuk * CAP;
    float* h1   = (float*)(ws + off); off += sizeof(float) * (size_t)n * DD;  // also h2
    float* agg1 = (float*)(ws + off); off += sizeof(float) * (size_t)n * DD;

    int ab = (n + 3) / 4;
    int gb = (n + 63) / 64;

    hipMemsetAsync(gcur, 0, sizeof(int) * MAXBUK, stream);
    k_bucket<<<nbuk, 256, 0, stream>>>(src, dst, buf, gcur, E, nbuk);
    k_scanbuk<<<1, 512, 0, stream>>>(gcur, bbase, nbuk, rowptr + n, E);
    k_csr<<<nbuk, 256, 0, stream>>>(buf, gcur, bbase, rowptr, rs, es, n);

    k_gemm1<<<gb, 256, 0, stream>>>(x, W1, rs, h1, n);
    k_agg<<<ab, 256, 0, stream>>>(h1, es, rowptr, rs, b1, p1, agg1, n);

    k_gemm2<<<gb, 256, 0, stream>>>(agg1, W2, rs, h1, n);
    k_agg<<<ab, 256, 0, stream>>>(h1, es, rowptr, rs, b2, p2, out, n);
}

// Round 7
// 224.893 us; speedup vs baseline: 2.1908x; 1.3317x over previous
//
#include <hip/hip_runtime.h>

#define DD 64
#define FIN 128
#define BK 256        // nodes per bucket
#define MAXBUK 512    // supports n <= 131072
#define CAP 8192      // records per bucket region (mean ~4092 at E=1.6M)

#define XS1 132       // padded x-tile stride (floats) for gemm1
#define XS2 68        // padded x-tile stride (floats) for gemm2

static __device__ __forceinline__ float4 f4fma(float a, float4 b, float4 c) {
    c.x = fmaf(a, b.x, c.x);
    c.y = fmaf(a, b.y, c.y);
    c.z = fmaf(a, b.z, c.z);
    c.w = fmaf(a, b.w, c.w);
    return c;
}

// round-to-nearest-even pack of two f32 into 2x bf16 (lo|hi)
static __device__ __forceinline__ unsigned bfpack(float lo, float hi) {
    unsigned ul = __float_as_uint(lo);
    unsigned uh = __float_as_uint(hi);
    ul += 0x7fffu + ((ul >> 16) & 1u);
    uh += 0x7fffu + ((uh >> 16) & 1u);
    return (ul >> 16) | (uh & 0xffff0000u);
}

// accumulate 8 bf16 (uint4) into 8 f32
static __device__ __forceinline__ void bfacc(uint4 v, float* a) {
    a[0] += __uint_as_float(v.x << 16);
    a[1] += __uint_as_float(v.x & 0xffff0000u);
    a[2] += __uint_as_float(v.y << 16);
    a[3] += __uint_as_float(v.y & 0xffff0000u);
    a[4] += __uint_as_float(v.z << 16);
    a[5] += __uint_as_float(v.z & 0xffff0000u);
    a[6] += __uint_as_float(v.w << 16);
    a[7] += __uint_as_float(v.w & 0xffff0000u);
}

// pass 1: bucket edges by dst>>8. LDS histogram -> one global atomic per
// (block,bucket) to reserve a range -> scatter packed (src<<8|dstlocal) u32.
__global__ __launch_bounds__(256) void k_bucket(const int* __restrict__ src,
                                                const int* __restrict__ dst,
                                                unsigned* __restrict__ buf,
                                                int* __restrict__ gcur,
                                                int E, int nbuk) {
    __shared__ int hist[MAXBUK];
    __shared__ int base[MAXBUK];
    int nb = gridDim.x;
    int chunk = (E + nb - 1) / nb;
    int e0 = blockIdx.x * chunk;
    int e1 = min(e0 + chunk, E);
    for (int i = threadIdx.x; i < nbuk; i += 256) hist[i] = 0;
    __syncthreads();
    for (int e = e0 + threadIdx.x; e < e1; e += 256)
        atomicAdd(&hist[dst[e] >> 8], 1);
    __syncthreads();
    for (int i = threadIdx.x; i < nbuk; i += 256) {
        int c = hist[i];
        base[i] = c ? atomicAdd(&gcur[i], c) : 0;
        hist[i] = 0;  // reuse as local cursor
    }
    __syncthreads();
    for (int e = e0 + threadIdx.x; e < e1; e += 256) {
        int d = dst[e];
        int b = d >> 8;
        int off = base[b] + atomicAdd(&hist[b], 1);
        if (off < CAP)
            buf[(size_t)b * CAP + off] = ((unsigned)src[e] << 8) | ((unsigned)d & 255u);
    }
}

// exclusive scan of bucket counts -> bucket base offsets; rowptr[n] = E
__global__ __launch_bounds__(512) void k_scanbuk(const int* __restrict__ gcur,
                                                 int* __restrict__ bbase, int nbuk,
                                                 int* __restrict__ rowptr_n, int E) {
    __shared__ int wsum[8];
    int v = (threadIdx.x < (unsigned)nbuk) ? gcur[threadIdx.x] : 0;
    int lane = threadIdx.x & 63, wid = threadIdx.x >> 6;
    int s = v;
    for (int off = 1; off < 64; off <<= 1) {
        int t = __shfl_up(s, off, 64);
        if (lane >= off) s += t;
    }
    if (lane == 63) wsum[wid] = s;
    __syncthreads();
    int wo = 0;
    for (int w = 0; w < wid; ++w) wo += wsum[w];
    if (threadIdx.x < (unsigned)nbuk) bbase[threadIdx.x] = s - v + wo;
    if (threadIdx.x == 0) *rowptr_n = E;
}

// pass 2: one workgroup per bucket -> per-node counts, scan, emit rowptr/rs/es
__global__ __launch_bounds__(256) void k_csr(const unsigned* __restrict__ buf,
                                             const int* __restrict__ gcur,
                                             const int* __restrict__ bbase,
                                             int* __restrict__ rowptr,
                                             float* __restrict__ rs,
                                             int* __restrict__ es, int n) {
    __shared__ int cnt[BK];
    __shared__ int excl[BK];
    __shared__ int cur[BK];
    __shared__ int wsum[4];
    int b = blockIdx.x;
    int count = gcur[b];
    int base = bbase[b];
    cnt[threadIdx.x] = 0;
    cur[threadIdx.x] = 0;
    __syncthreads();
    const unsigned* rec = buf + (size_t)b * CAP;
    for (int i = threadIdx.x; i < count; i += 256)
        atomicAdd(&cnt[rec[i] & (BK - 1)], 1);
    __syncthreads();
    int lane = threadIdx.x & 63, wid = threadIdx.x >> 6;
    int v = cnt[threadIdx.x];
    int s = v;
    for (int off = 1; off < 64; off <<= 1) {
        int t = __shfl_up(s, off, 64);
        if (lane >= off) s += t;
    }
    if (lane == 63) wsum[wid] = s;
    __syncthreads();
    int wo = 0;
    for (int w = 0; w < wid; ++w) wo += wsum[w];
    excl[threadIdx.x] = s - v + wo;
    __syncthreads();
    int node = b * BK + threadIdx.x;
    if (node < n) {
        rowptr[node] = base + excl[threadIdx.x];
        rs[node] = rsqrtf((float)(v + 1));  // +1 self-loop
    }
    for (int i = threadIdx.x; i < count; i += 256) {
        unsigned r = rec[i];
        int local = r & (BK - 1);
        int pos = base + excl[local] + atomicAdd(&cur[local], 1);
        es[pos] = (int)(r >> 8);
    }
}

// LDS-tiled GEMM: out[64rows x 64cols] per block, thread = 4x4 tile.
// hpb[row][col] = bf16((x[row,:] @ W[:,col]) * rs[row])
__global__ __launch_bounds__(256) void k_gemm1(const float* __restrict__ x,
                                               const float* __restrict__ W,
                                               const float* __restrict__ rs,
                                               unsigned* __restrict__ hpb, int n) {
    __shared__ float sx[64 * XS1];
    __shared__ float sW[FIN * DD];
    int row0 = blockIdx.x * 64;
    for (int i = threadIdx.x; i < FIN * DD / 4; i += 256)
        ((float4*)sW)[i] = ((const float4*)W)[i];
    for (int i = threadIdx.x; i < 64 * FIN / 4; i += 256) {
        int r = i >> 5;           // 32 float4 per row
        int c = i & 31;
        int row = row0 + r;
        float4 v = make_float4(0.f, 0.f, 0.f, 0.f);
        if (row < n) v = *(const float4*)(x + (size_t)row * FIN + c * 4);
        *(float4*)(sx + r * XS1 + c * 4) = v;
    }
    __syncthreads();
    int col4 = (threadIdx.x & 15) * 4;
    int rowg = threadIdx.x >> 4;  // 0..15
    float4 acc[4] = {make_float4(0,0,0,0), make_float4(0,0,0,0),
                     make_float4(0,0,0,0), make_float4(0,0,0,0)};
#pragma unroll 8
    for (int k = 0; k < FIN; k += 4) {
        float4 w0 = *(const float4*)(sW + k * DD + col4);
        float4 w1 = *(const float4*)(sW + (k + 1) * DD + col4);
        float4 w2 = *(const float4*)(sW + (k + 2) * DD + col4);
        float4 w3 = *(const float4*)(sW + (k + 3) * DD + col4);
#pragma unroll
        for (int r = 0; r < 4; ++r) {
            float4 xv = *(const float4*)(sx + (rowg * 4 + r) * XS1 + k);
            acc[r] = f4fma(xv.x, w0, acc[r]);
            acc[r] = f4fma(xv.y, w1, acc[r]);
            acc[r] = f4fma(xv.z, w2, acc[r]);
            acc[r] = f4fma(xv.w, w3, acc[r]);
        }
    }
#pragma unroll
    for (int r = 0; r < 4; ++r) {
        int row = row0 + rowg * 4 + r;
        if (row < n) {
            float sc = rs[row];
            uint2 pk;
            pk.x = bfpack(acc[r].x * sc, acc[r].y * sc);
            pk.y = bfpack(acc[r].z * sc, acc[r].w * sc);
            *(uint2*)(hpb + (size_t)row * 32 + (col4 >> 1)) = pk;
        }
    }
}

// hpb[row][col] = bf16((relu(a[row,:]) @ W[:,col]) * rs[row])
__global__ __launch_bounds__(256) void k_gemm2(const float* __restrict__ a,
                                               const float* __restrict__ W,
                                               const float* __restrict__ rs,
                                               unsigned* __restrict__ hpb, int n) {
    __shared__ float sx[64 * XS2];
    __shared__ float sW[DD * DD];
    int row0 = blockIdx.x * 64;
    for (int i = threadIdx.x; i < DD * DD / 4; i += 256)
        ((float4*)sW)[i] = ((const float4*)W)[i];
    for (int i = threadIdx.x; i < 64 * DD / 4; i += 256) {
        int r = i >> 4;           // 16 float4 per row
        int c = i & 15;
        int row = row0 + r;
        float4 v = make_float4(0.f, 0.f, 0.f, 0.f);
        if (row < n) {
            v = *(const float4*)(a + (size_t)row * DD + c * 4);
            v.x = fmaxf(v.x, 0.f); v.y = fmaxf(v.y, 0.f);
            v.z = fmaxf(v.z, 0.f); v.w = fmaxf(v.w, 0.f);
        }
        *(float4*)(sx + r * XS2 + c * 4) = v;
    }
    __syncthreads();
    int col4 = (threadIdx.x & 15) * 4;
    int rowg = threadIdx.x >> 4;
    float4 acc[4] = {make_float4(0,0,0,0), make_float4(0,0,0,0),
                     make_float4(0,0,0,0), make_float4(0,0,0,0)};
#pragma unroll 8
    for (int k = 0; k < DD; k += 4) {
        float4 w0 = *(const float4*)(sW + k * DD + col4);
        float4 w1 = *(const float4*)(sW + (k + 1) * DD + col4);
        float4 w2 = *(const float4*)(sW + (k + 2) * DD + col4);
        float4 w3 = *(const float4*)(sW + (k + 3) * DD + col4);
#pragma unroll
        for (int r = 0; r < 4; ++r) {
            float4 xv = *(const float4*)(sx + (rowg * 4 + r) * XS2 + k);
            acc[r] = f4fma(xv.x, w0, acc[r]);
            acc[r] = f4fma(xv.y, w1, acc[r]);
            acc[r] = f4fma(xv.z, w2, acc[r]);
            acc[r] = f4fma(xv.w, w3, acc[r]);
        }
    }
#pragma unroll
    for (int r = 0; r < 4; ++r) {
        int row = row0 + rowg * 4 + r;
        if (row < n) {
            float sc = rs[row];
            uint2 pk;
            pk.x = bfpack(acc[r].x * sc, acc[r].y * sc);
            pk.y = bfpack(acc[r].z * sc, acc[r].w * sc);
            *(uint2*)(hpb + (size_t)row * 32 + (col4 >> 1)) = pk;
        }
    }
}

// gather aggregation: one wave per node; 8 groups x 8 lanes; each group gathers
// one edge's bf16 row (128B) as uint4/lane. out[d] = b + pert[d] + rs[d]*sum
__global__ __launch_bounds__(256) void k_agg(const uint4* __restrict__ hp4,
                                             const int* __restrict__ es,
                                             const int* __restrict__ rowptr,
                                             const float* __restrict__ rs,
                                             const float* __restrict__ b,
                                             const float* __restrict__ pert,
                                             float* __restrict__ outp, int n) {
    int lane = threadIdx.x & 63;
    int w = threadIdx.x >> 6;
    int node = blockIdx.x * 4 + w;
    if (node >= n) return;
    node = __builtin_amdgcn_readfirstlane(node);
    int grp = lane >> 3, sub = lane & 7;
    int e0 = rowptr[node], e1 = rowptr[node + 1];
    float accA[8] = {0,0,0,0,0,0,0,0};
    float accB[8] = {0,0,0,0,0,0,0,0};
    if (grp == 0)  // self-loop term
        bfacc(hp4[(size_t)node * 8 + sub], accA);
    int e = e0 + grp;
    for (; e + 8 < e1; e += 16) {
        int sA = es[e];
        int sB = es[e + 8];
        uint4 va = hp4[(size_t)sA * 8 + sub];
        uint4 vb = hp4[(size_t)sB * 8 + sub];
        bfacc(va, accA);
        bfacc(vb, accB);
    }
    if (e < e1)
        bfacc(hp4[(size_t)es[e] * 8 + sub], accA);
#pragma unroll
    for (int j = 0; j < 8; ++j) {
        float v = accA[j] + accB[j];
        v += __shfl_xor(v, 8, 64);
        v += __shfl_xor(v, 16, 64);
        v += __shfl_xor(v, 32, 64);
        accA[j] = v;
    }
    if (grp == 0) {
        size_t o = (size_t)node * DD + sub * 8;
        float r = rs[node];
        float4 p0 = *(const float4*)(pert + o);
        float4 p1 = *(const float4*)(pert + o + 4);
        float4 b0 = *(const float4*)(b + sub * 8);
        float4 b1 = *(const float4*)(b + sub * 8 + 4);
        float4 r0, r1;
        r0.x = fmaf(r, accA[0], b0.x + p0.x);
        r0.y = fmaf(r, accA[1], b0.y + p0.y);
        r0.z = fmaf(r, accA[2], b0.z + p0.z);
        r0.w = fmaf(r, accA[3], b0.w + p0.w);
        r1.x = fmaf(r, accA[4], b1.x + p1.x);
        r1.y = fmaf(r, accA[5], b1.y + p1.y);
        r1.z = fmaf(r, accA[6], b1.z + p1.z);
        r1.w = fmaf(r, accA[7], b1.w + p1.w);
        *(float4*)(outp + o) = r0;
        *(float4*)(outp + o + 4) = r1;
    }
}

extern "C" void kernel_launch(void* const* d_in, const int* in_sizes, int n_in,
                              void* d_out, int out_size, void* d_ws, size_t ws_size,
                              hipStream_t stream) {
    const float* x  = (const float*)d_in[0];
    const int*   ei = (const int*)d_in[1];
    const float* W1 = (const float*)d_in[2];
    const float* b1 = (const float*)d_in[3];
    const float* W2 = (const float*)d_in[4];
    const float* b2 = (const float*)d_in[5];
    const float* p1 = (const float*)d_in[6];
    const float* p2 = (const float*)d_in[7];
    float* out = (float*)d_out;

    int n = in_sizes[0] / FIN;
    int E = in_sizes[1] / 2;
    const int* src = ei;
    const int* dst = ei + E;
    int nbuk = (n + BK - 1) / BK;  // 391 for n=100k

    char* ws = (char*)d_ws;
    size_t off = 0;
    int* gcur   = (int*)(ws + off); off += sizeof(int) * MAXBUK;
    int* bbase  = (int*)(ws + off); off += sizeof(int) * MAXBUK;
    int* rowptr = (int*)(ws + off); off += sizeof(int) * (size_t)(n + 1);
    float* rs   = (float*)(ws + off); off += sizeof(float) * (size_t)n;
    int* es     = (int*)(ws + off); off += sizeof(int) * (size_t)E;
    off = (off + 15) & ~(size_t)15;
    unsigned* buf = (unsigned*)(ws + off);
    off += sizeof(unsigned) * (size_t)nbuk * CAP;
    off = (off + 15) & ~(size_t)15;
    unsigned* hpb = (unsigned*)(ws + off);      // bf16 [n][64] = n*128 bytes
    off += (size_t)n * 128;
    float* agg1 = (float*)(ws + off); off += sizeof(float) * (size_t)n * DD;

    int ab = (n + 3) / 4;
    int gb = (n + 63) / 64;

    hipMemsetAsync(gcur, 0, sizeof(int) * MAXBUK, stream);
    k_bucket<<<nbuk, 256, 0, stream>>>(src, dst, buf, gcur, E, nbuk);
    k_scanbuk<<<1, 512, 0, stream>>>(gcur, bbase, nbuk, rowptr + n, E);
    k_csr<<<nbuk, 256, 0, stream>>>(buf, gcur, bbase, rowptr, rs, es, n);

    k_gemm1<<<gb, 256, 0, stream>>>(x, W1, rs, hpb, n);
    k_agg<<<ab, 256, 0, stream>>>((const uint4*)hpb, es, rowptr, rs, b1, p1, agg1, n);

    k_gemm2<<<gb, 256, 0, stream>>>(agg1, W2, rs, hpb, n);
    k_agg<<<ab, 256, 0, stream>>>((const uint4*)hpb, es, rowptr, rs, b2, p2, out, n);
}

// Round 8
// 214.251 us; speedup vs baseline: 2.2997x; 1.0497x over previous
//
#include <hip/hip_runtime.h>

#define DD 64
#define FIN 128
#define BK 256        // nodes per bucket
#define MAXBUK 512    // supports n <= 131072
#define CAP 8192      // records per bucket region (mean ~4092 at E=1.6M)
#define EPB 4096      // edges per k_bucket block (16 per thread)

#define XS1 132       // padded x-tile stride (floats) for gemm1
#define XS2 68        // padded x-tile stride (floats) for gemm2

static __device__ __forceinline__ float4 f4fma(float a, float4 b, float4 c) {
    c.x = fmaf(a, b.x, c.x);
    c.y = fmaf(a, b.y, c.y);
    c.z = fmaf(a, b.z, c.z);
    c.w = fmaf(a, b.w, c.w);
    return c;
}

// round-to-nearest-even pack of two f32 into 2x bf16 (lo|hi)
static __device__ __forceinline__ unsigned bfpack(float lo, float hi) {
    unsigned ul = __float_as_uint(lo);
    unsigned uh = __float_as_uint(hi);
    ul += 0x7fffu + ((ul >> 16) & 1u);
    uh += 0x7fffu + ((uh >> 16) & 1u);
    return (ul >> 16) | (uh & 0xffff0000u);
}

// accumulate 8 bf16 (uint4) into 8 f32
static __device__ __forceinline__ void bfacc(uint4 v, float* a) {
    a[0] += __uint_as_float(v.x << 16);
    a[1] += __uint_as_float(v.x & 0xffff0000u);
    a[2] += __uint_as_float(v.y << 16);
    a[3] += __uint_as_float(v.y & 0xffff0000u);
    a[4] += __uint_as_float(v.z << 16);
    a[5] += __uint_as_float(v.z & 0xffff0000u);
    a[6] += __uint_as_float(v.w << 16);
    a[7] += __uint_as_float(v.w & 0xffff0000u);
}

// pass 1: bucket edges by dst>>8. dst values cached in regs across both passes.
__global__ __launch_bounds__(256) void k_bucket(const int* __restrict__ src,
                                                const int* __restrict__ dst,
                                                unsigned* __restrict__ buf,
                                                int* __restrict__ gcur,
                                                int E, int nbuk) {
    __shared__ int hist[MAXBUK];
    __shared__ int base[MAXBUK];
    int e0 = blockIdx.x * EPB;
    int e1 = min(e0 + EPB, E);
    int dreg[16];
#pragma unroll
    for (int i = 0; i < 16; ++i) {
        int e = e0 + threadIdx.x + i * 256;
        dreg[i] = (e < e1) ? dst[e] : -1;
    }
    for (int i = threadIdx.x; i < nbuk; i += 256) hist[i] = 0;
    __syncthreads();
#pragma unroll
    for (int i = 0; i < 16; ++i)
        if (dreg[i] >= 0) atomicAdd(&hist[dreg[i] >> 8], 1);
    __syncthreads();
    for (int i = threadIdx.x; i < nbuk; i += 256) {
        int c = hist[i];
        base[i] = c ? atomicAdd(&gcur[i], c) : 0;
        hist[i] = 0;  // reuse as local cursor
    }
    __syncthreads();
#pragma unroll
    for (int i = 0; i < 16; ++i) {
        int d = dreg[i];
        if (d >= 0) {
            int e = e0 + threadIdx.x + i * 256;
            int b = d >> 8;
            int off = base[b] + atomicAdd(&hist[b], 1);
            if (off < CAP)
                buf[(size_t)b * CAP + off] = ((unsigned)src[e] << 8) | ((unsigned)d & 255u);
        }
    }
}

// pass 2 (scan fused): one workgroup per bucket -> prefix over gcur, per-node
// counts, scan, emit rowptr/rs/es. Last block writes rowptr[n] = E.
__global__ __launch_bounds__(256) void k_csr(const unsigned* __restrict__ buf,
                                             const int* __restrict__ gcur,
                                             int* __restrict__ rowptr,
                                             float* __restrict__ rs,
                                             int* __restrict__ es, int n, int nbuk) {
    __shared__ int cnt[BK];
    __shared__ int excl[BK];
    __shared__ int cur[BK];
    __shared__ int wsum[4];
    __shared__ int pw[4];
    __shared__ int sbase;
    int b = blockIdx.x;
    int tid = threadIdx.x;
    int lane = tid & 63, wid = tid >> 6;
    // inline exclusive prefix: base = sum gcur[0..b)
    int partial = 0;
    for (int i = tid; i < b; i += 256) partial += gcur[i];
    for (int o = 32; o; o >>= 1) partial += __shfl_down(partial, o, 64);
    if (lane == 0) pw[wid] = partial;
    cnt[tid] = 0;
    cur[tid] = 0;
    __syncthreads();
    if (tid == 0) sbase = pw[0] + pw[1] + pw[2] + pw[3];
    __syncthreads();
    int base = sbase;
    int count = gcur[b];
    const unsigned* rec = buf + (size_t)b * CAP;
    for (int i = tid; i < count; i += 256)
        atomicAdd(&cnt[rec[i] & (BK - 1)], 1);
    __syncthreads();
    int v = cnt[tid];
    int s = v;
    for (int off = 1; off < 64; off <<= 1) {
        int t = __shfl_up(s, off, 64);
        if (lane >= off) s += t;
    }
    if (lane == 63) wsum[wid] = s;
    __syncthreads();
    int wo = 0;
    for (int w = 0; w < wid; ++w) wo += wsum[w];
    excl[tid] = s - v + wo;
    __syncthreads();
    int node = b * BK + tid;
    if (node < n) {
        rowptr[node] = base + excl[tid];
        rs[node] = rsqrtf((float)(v + 1));  // +1 self-loop
    }
    if (tid == 0 && b == nbuk - 1) rowptr[n] = base + count;
    for (int i = tid; i < count; i += 256) {
        unsigned r = rec[i];
        int local = r & (BK - 1);
        int pos = base + excl[local] + atomicAdd(&cur[local], 1);
        es[pos] = (int)(r >> 8);
    }
}

// LDS-tiled GEMM: out[64rows x 64cols] per block, thread = 4x4 tile.
// hpb[row][col] = bf16((x[row,:] @ W[:,col]) * rs[row])
__global__ __launch_bounds__(256) void k_gemm1(const float* __restrict__ x,
                                               const float* __restrict__ W,
                                               const float* __restrict__ rs,
                                               unsigned* __restrict__ hpb, int n) {
    __shared__ float sx[64 * XS1];
    __shared__ float sW[FIN * DD];
    int row0 = blockIdx.x * 64;
    for (int i = threadIdx.x; i < FIN * DD / 4; i += 256)
        ((float4*)sW)[i] = ((const float4*)W)[i];
    for (int i = threadIdx.x; i < 64 * FIN / 4; i += 256) {
        int r = i >> 5;           // 32 float4 per row
        int c = i & 31;
        int row = row0 + r;
        float4 v = make_float4(0.f, 0.f, 0.f, 0.f);
        if (row < n) v = *(const float4*)(x + (size_t)row * FIN + c * 4);
        *(float4*)(sx + r * XS1 + c * 4) = v;
    }
    __syncthreads();
    int col4 = (threadIdx.x & 15) * 4;
    int rowg = threadIdx.x >> 4;  // 0..15
    float4 acc[4] = {make_float4(0,0,0,0), make_float4(0,0,0,0),
                     make_float4(0,0,0,0), make_float4(0,0,0,0)};
#pragma unroll 8
    for (int k = 0; k < FIN; k += 4) {
        float4 w0 = *(const float4*)(sW + k * DD + col4);
        float4 w1 = *(const float4*)(sW + (k + 1) * DD + col4);
        float4 w2 = *(const float4*)(sW + (k + 2) * DD + col4);
        float4 w3 = *(const float4*)(sW + (k + 3) * DD + col4);
#pragma unroll
        for (int r = 0; r < 4; ++r) {
            float4 xv = *(const float4*)(sx + (rowg * 4 + r) * XS1 + k);
            acc[r] = f4fma(xv.x, w0, acc[r]);
            acc[r] = f4fma(xv.y, w1, acc[r]);
            acc[r] = f4fma(xv.z, w2, acc[r]);
            acc[r] = f4fma(xv.w, w3, acc[r]);
        }
    }
#pragma unroll
    for (int r = 0; r < 4; ++r) {
        int row = row0 + rowg * 4 + r;
        if (row < n) {
            float sc = rs[row];
            uint2 pk;
            pk.x = bfpack(acc[r].x * sc, acc[r].y * sc);
            pk.y = bfpack(acc[r].z * sc, acc[r].w * sc);
            *(uint2*)(hpb + (size_t)row * 32 + (col4 >> 1)) = pk;
        }
    }
}

// hpb[row][col] = bf16((relu(a[row,:]) @ W[:,col]) * rs[row])
__global__ __launch_bounds__(256) void k_gemm2(const float* __restrict__ a,
                                               const float* __restrict__ W,
                                               const float* __restrict__ rs,
                                               unsigned* __restrict__ hpb, int n) {
    __shared__ float sx[64 * XS2];
    __shared__ float sW[DD * DD];
    int row0 = blockIdx.x * 64;
    for (int i = threadIdx.x; i < DD * DD / 4; i += 256)
        ((float4*)sW)[i] = ((const float4*)W)[i];
    for (int i = threadIdx.x; i < 64 * DD / 4; i += 256) {
        int r = i >> 4;           // 16 float4 per row
        int c = i & 15;
        int row = row0 + r;
        float4 v = make_float4(0.f, 0.f, 0.f, 0.f);
        if (row < n) {
            v = *(const float4*)(a + (size_t)row * DD + c * 4);
            v.x = fmaxf(v.x, 0.f); v.y = fmaxf(v.y, 0.f);
            v.z = fmaxf(v.z, 0.f); v.w = fmaxf(v.w, 0.f);
        }
        *(float4*)(sx + r * XS2 + c * 4) = v;
    }
    __syncthreads();
    int col4 = (threadIdx.x & 15) * 4;
    int rowg = threadIdx.x >> 4;
    float4 acc[4] = {make_float4(0,0,0,0), make_float4(0,0,0,0),
                     make_float4(0,0,0,0), make_float4(0,0,0,0)};
#pragma unroll 8
    for (int k = 0; k < DD; k += 4) {
        float4 w0 = *(const float4*)(sW + k * DD + col4);
        float4 w1 = *(const float4*)(sW + (k + 1) * DD + col4);
        float4 w2 = *(const float4*)(sW + (k + 2) * DD + col4);
        float4 w3 = *(const float4*)(sW + (k + 3) * DD + col4);
#pragma unroll
        for (int r = 0; r < 4; ++r) {
            float4 xv = *(const float4*)(sx + (rowg * 4 + r) * XS2 + k);
            acc[r] = f4fma(xv.x, w0, acc[r]);
            acc[r] = f4fma(xv.y, w1, acc[r]);
            acc[r] = f4fma(xv.z, w2, acc[r]);
            acc[r] = f4fma(xv.w, w3, acc[r]);
        }
    }
#pragma unroll
    for (int r = 0; r < 4; ++r) {
        int row = row0 + rowg * 4 + r;
        if (row < n) {
            float sc = rs[row];
            uint2 pk;
            pk.x = bfpack(acc[r].x * sc, acc[r].y * sc);
            pk.y = bfpack(acc[r].z * sc, acc[r].w * sc);
            *(uint2*)(hpb + (size_t)row * 32 + (col4 >> 1)) = pk;
        }
    }
}

// gather aggregation: 4 nodes per wave (16 lanes/node = 2 edge-slots x 8 lanes,
// uint4 each). 4-deep unroll -> 32 rows in flight per wave. 1 shfl step.
// out[d] = b + pert[d] + rs[d]*(hp[d] + sum hp[src])
__global__ __launch_bounds__(256) void k_agg(const uint4* __restrict__ hp4,
                                             const int* __restrict__ es,
                                             const int* __restrict__ rowptr,
                                             const float* __restrict__ rs,
                                             const float* __restrict__ b,
                                             const float* __restrict__ pert,
                                             float* __restrict__ outp, int n) {
    int lane = threadIdx.x & 63;
    int wv = threadIdx.x >> 6;
    int g = lane >> 4;            // node sub-group 0..3
    int sub = lane & 15;
    int eslot = sub >> 3;         // 0..1
    int q = sub & 7;              // uint4 index within 128B row
    int node = (blockIdx.x * 4 + wv) * 4 + g;
    bool alive = node < n;
    int nc = alive ? node : 0;
    int e0 = rowptr[nc];
    int e1 = alive ? rowptr[nc + 1] : e0;
    float A[8] = {0,0,0,0,0,0,0,0};
    float B[8] = {0,0,0,0,0,0,0,0};
    float C[8] = {0,0,0,0,0,0,0,0};
    float D[8] = {0,0,0,0,0,0,0,0};
    if (alive && eslot == 0) bfacc(hp4[(size_t)nc * 8 + q], A);  // self-loop
    int e = e0 + eslot;
    for (; e + 6 < e1; e += 8) {
        uint4 va = hp4[(size_t)es[e] * 8 + q];
        uint4 vb = hp4[(size_t)es[e + 2] * 8 + q];
        uint4 vc = hp4[(size_t)es[e + 4] * 8 + q];
        uint4 vd = hp4[(size_t)es[e + 6] * 8 + q];
        bfacc(va, A); bfacc(vb, B); bfacc(vc, C); bfacc(vd, D);
    }
    for (; e < e1; e += 2) bfacc(hp4[(size_t)es[e] * 8 + q], A);
#pragma unroll
    for (int j = 0; j < 8; ++j) {
        float v = (A[j] + B[j]) + (C[j] + D[j]);
        v += __shfl_xor(v, 8, 64);  // combine the 2 edge slots
        A[j] = v;
    }
    if (alive && eslot == 0) {
        float r = rs[nc];
        size_t o = (size_t)nc * DD + q * 8;
        float4 p0 = *(const float4*)(pert + o);
        float4 p1 = *(const float4*)(pert + o + 4);
        float4 b0 = *(const float4*)(b + q * 8);
        float4 b1 = *(const float4*)(b + q * 8 + 4);
        float4 r0, r1;
        r0.x = fmaf(r, A[0], b0.x + p0.x);
        r0.y = fmaf(r, A[1], b0.y + p0.y);
        r0.z = fmaf(r, A[2], b0.z + p0.z);
        r0.w = fmaf(r, A[3], b0.w + p0.w);
        r1.x = fmaf(r, A[4], b1.x + p1.x);
        r1.y = fmaf(r, A[5], b1.y + p1.y);
        r1.z = fmaf(r, A[6], b1.z + p1.z);
        r1.w = fmaf(r, A[7], b1.w + p1.w);
        *(float4*)(outp + o) = r0;
        *(float4*)(outp + o + 4) = r1;
    }
}

extern "C" void kernel_launch(void* const* d_in, const int* in_sizes, int n_in,
                              void* d_out, int out_size, void* d_ws, size_t ws_size,
                              hipStream_t stream) {
    const float* x  = (const float*)d_in[0];
    const int*   ei = (const int*)d_in[1];
    const float* W1 = (const float*)d_in[2];
    const float* b1 = (const float*)d_in[3];
    const float* W2 = (const float*)d_in[4];
    const float* b2 = (const float*)d_in[5];
    const float* p1 = (const float*)d_in[6];
    const float* p2 = (const float*)d_in[7];
    float* out = (float*)d_out;

    int n = in_sizes[0] / FIN;
    int E = in_sizes[1] / 2;
    const int* src = ei;
    const int* dst = ei + E;
    int nbuk = (n + BK - 1) / BK;  // 391 for n=100k

    char* ws = (char*)d_ws;
    size_t off = 0;
    int* gcur   = (int*)(ws + off); off += sizeof(int) * MAXBUK;
    int* rowptr = (int*)(ws + off); off += sizeof(int) * (size_t)(n + 1);
    float* rs   = (float*)(ws + off); off += sizeof(float) * (size_t)n;
    int* es     = (int*)(ws + off); off += sizeof(int) * (size_t)E;
    off = (off + 15) & ~(size_t)15;
    unsigned* buf = (unsigned*)(ws + off);
    off += sizeof(unsigned) * (size_t)nbuk * CAP;
    off = (off + 15) & ~(size_t)15;
    unsigned* hpb = (unsigned*)(ws + off);      // bf16 [n][64] = n*128 bytes
    off += (size_t)n * 128;
    float* agg1 = (float*)(ws + off); off += sizeof(float) * (size_t)n * DD;

    int ab = (n + 15) / 16;        // 4 nodes per wave, 4 waves per block
    int gb = (n + 63) / 64;
    int bb = (E + EPB - 1) / EPB;

    hipMemsetAsync(gcur, 0, sizeof(int) * MAXBUK, stream);
    k_bucket<<<bb, 256, 0, stream>>>(src, dst, buf, gcur, E, nbuk);
    k_csr<<<nbuk, 256, 0, stream>>>(buf, gcur, rowptr, rs, es, n, nbuk);

    k_gemm1<<<gb, 256, 0, stream>>>(x, W1, rs, hpb, n);
    k_agg<<<ab, 256, 0, stream>>>((const uint4*)hpb, es, rowptr, rs, b1, p1, agg1, n);

    k_gemm2<<<gb, 256, 0, stream>>>(agg1, W2, rs, hpb, n);
    k_agg<<<ab, 256, 0, stream>>>((const uint4*)hpb, es, rowptr, rs, b2, p2, out, n);
}